// Round 1
// baseline (1174.993 us; speedup 1.0000x reference)
//
#include <hip/hip_runtime.h>

#define K_CLS 80
#define WDIM  300

// ---------------------------------------------------------------------------
// fd[k][d] = (sum_w word[k,w] * W2[d,w]) * 2*log2(e)   (pre-scaled for tanh)
// ---------------------------------------------------------------------------
__global__ __launch_bounds__(256) void k_fd(const float* __restrict__ word,
                                            const float* __restrict__ W2,
                                            float* __restrict__ fd, int D) {
    int idx = blockIdx.x * blockDim.x + threadIdx.x;
    if (idx >= K_CLS * D) return;
    int k = idx / D;
    int d = idx - k * D;
    const float4* wr = (const float4*)(word + (size_t)k * WDIM);
    const float4* w2 = (const float4*)(W2 + (size_t)d * WDIM);
    float acc = 0.f;
#pragma unroll 5
    for (int j = 0; j < WDIM / 4; ++j) {
        float4 a = wr[j], b = w2[j];
        acc += a.x * b.x + a.y * b.y + a.z * b.z + a.w * b.w;
    }
    fd[idx] = acc * 2.885390081777927f;  // 2*log2(e)
}

// ---------------------------------------------------------------------------
// v[d] = sum_e Wa[e] * W3[e,d]
// ---------------------------------------------------------------------------
__global__ __launch_bounds__(256) void k_v(const float* __restrict__ Wa,
                                           const float* __restrict__ W3,
                                           float* __restrict__ v, int D) {
    int d = blockIdx.x * blockDim.x + threadIdx.x;
    if (d >= D) return;
    float acc = 0.f;
    for (int e = 0; e < D; ++e) acc += Wa[e] * W3[(size_t)e * D + d];
    v[d] = acc;
}

// ---------------------------------------------------------------------------
// fw[b*HW+hw][d] = sum_c fmap[b][c][hw] * W1[d][c]
// fp32 tiled GEMM, 64x64 tile, TK=16, 4x4 micro-tile. grid (D/64, ceil(HW/64), B)
// ---------------------------------------------------------------------------
__global__ __launch_bounds__(256) void k_fw(const float* __restrict__ fmap,
                                            const float* __restrict__ W1,
                                            float* __restrict__ fw,
                                            int C, int HW, int D) {
    __shared__ float As[16][64];  // [kk][mm]
    __shared__ float Bs[16][64];  // [kk][dd]
    int b   = blockIdx.z;
    int hw0 = blockIdx.y * 64;
    int d0  = blockIdx.x * 64;
    int tid = threadIdx.x;
    int tx = tid & 15, ty = tid >> 4;
    const float* fb = fmap + (size_t)b * C * HW;
    float acc[4][4] = {};

    int mmA = tid & 63, kbA = (tid >> 6) * 4;
    int ddB = tid >> 2, kpB = (tid & 3) * 4;
    int hwA = hw0 + mmA;
    bool okA = hwA < HW;

    for (int k0 = 0; k0 < C; k0 += 16) {
#pragma unroll
        for (int i = 0; i < 4; ++i) {
            float val = okA ? fb[(size_t)(k0 + kbA + i) * HW + hwA] : 0.f;
            As[kbA + i][mmA] = val;
        }
        float4 w4 = *(const float4*)(W1 + (size_t)(d0 + ddB) * C + k0 + kpB);
        Bs[kpB + 0][ddB] = w4.x;
        Bs[kpB + 1][ddB] = w4.y;
        Bs[kpB + 2][ddB] = w4.z;
        Bs[kpB + 3][ddB] = w4.w;
        __syncthreads();
#pragma unroll
        for (int kk = 0; kk < 16; ++kk) {
            float4 a4 = *(const float4*)&As[kk][ty * 4];
            float4 b4 = *(const float4*)&Bs[kk][tx * 4];
            float av[4] = {a4.x, a4.y, a4.z, a4.w};
            float bv[4] = {b4.x, b4.y, b4.z, b4.w};
#pragma unroll
            for (int i = 0; i < 4; ++i)
#pragma unroll
                for (int j = 0; j < 4; ++j) acc[i][j] += av[i] * bv[j];
        }
        __syncthreads();
    }
#pragma unroll
    for (int i = 0; i < 4; ++i) {
        int hw = hw0 + ty * 4 + i;
        if (hw < HW) {
            float4 o = {acc[i][0], acc[i][1], acc[i][2], acc[i][3]};
            *(float4*)(fw + ((size_t)b * HW + hw) * D + d0 + tx * 4) = o;
        }
    }
}

// ---------------------------------------------------------------------------
// score[b][k][hw] = -2 * sum_d v[d] * rcp(exp2(fw[m,d]*fd2[k,d]) + 1)
// (== sum_d tanh(fw*fd)*v[d] up to an additive constant that cancels in softmax)
// block = 320 threads = 5 waves; wave w covers k = 16w..16w+15; 4 lanes per k
// split d into quarters. grid = B*HW.
// ---------------------------------------------------------------------------
__global__ __launch_bounds__(320) void k_score(const float* __restrict__ fw,
                                               const float* __restrict__ fd,
                                               const float* __restrict__ v,
                                               float* __restrict__ score,
                                               int D, int HW) {
    int m = blockIdx.x;  // b*HW + hw
    int b = m / HW, hw = m - b * HW;
    int tid = threadIdx.x;
    int wave = tid >> 6, lane = tid & 63;
    int kk = lane >> 2, ds = lane & 3;
    int k = wave * 16 + kk;
    int DS = D >> 2;
    const float4* fwp = (const float4*)(fw + (size_t)m * D + ds * DS);
    const float4* fdp = (const float4*)(fd + (size_t)k * D + ds * DS);
    const float4* vp  = (const float4*)(v + ds * DS);
    float acc = 0.f;
    int n4 = DS >> 2;
    for (int j = 0; j < n4; ++j) {
        float4 a = fwp[j], f = fdp[j], vv = vp[j];
        acc += vv.x * __builtin_amdgcn_rcpf(__builtin_amdgcn_exp2f(a.x * f.x) + 1.0f);
        acc += vv.y * __builtin_amdgcn_rcpf(__builtin_amdgcn_exp2f(a.y * f.y) + 1.0f);
        acc += vv.z * __builtin_amdgcn_rcpf(__builtin_amdgcn_exp2f(a.z * f.z) + 1.0f);
        acc += vv.w * __builtin_amdgcn_rcpf(__builtin_amdgcn_exp2f(a.w * f.w) + 1.0f);
    }
    acc += __shfl_xor(acc, 1);
    acc += __shfl_xor(acc, 2);
    if (ds == 0) score[((size_t)b * K_CLS + k) * HW + hw] = -2.0f * acc;
}

// ---------------------------------------------------------------------------
// per (b,k): p = exp(score - max); inv = 1/sum(p). In-place on score buffer.
// grid = B*K, 256 threads.
// ---------------------------------------------------------------------------
__global__ __launch_bounds__(256) void k_softmax(float* __restrict__ score,
                                                 float* __restrict__ inv, int HW) {
    __shared__ float redm[4];
    __shared__ float reds[4];
    int bk = blockIdx.x;
    float* row = score + (size_t)bk * HW;
    int tid = threadIdx.x, lane = tid & 63, wave = tid >> 6;
    float mx = -1e30f;
    for (int i = tid; i < HW; i += 256) mx = fmaxf(mx, row[i]);
#pragma unroll
    for (int o = 32; o >= 1; o >>= 1) mx = fmaxf(mx, __shfl_xor(mx, o));
    if (lane == 0) redm[wave] = mx;
    __syncthreads();
    mx = fmaxf(fmaxf(redm[0], redm[1]), fmaxf(redm[2], redm[3]));
    float sum = 0.f;
    for (int i = tid; i < HW; i += 256) {
        float e = __builtin_amdgcn_exp2f((row[i] - mx) * 1.4426950408889634f);
        row[i] = e;
        sum += e;
    }
#pragma unroll
    for (int o = 32; o >= 1; o >>= 1) sum += __shfl_xor(sum, o);
    if (lane == 0) reds[wave] = sum;
    __syncthreads();
    if (tid == 0) inv[bk] = 1.0f / (reds[0] + reds[1] + reds[2] + reds[3]);
}

// ---------------------------------------------------------------------------
// out[b][k][c] = inv[b,k] * sum_hw p[b][k][hw] * fmap[b][c][hw]
// LDS-tiled: 40 k x 32 c per block, hw chunks of 128. grid (C/32, 2, B)
// ---------------------------------------------------------------------------
#define CHUNK 128
__global__ __launch_bounds__(256) void k_pool(const float* __restrict__ p,
                                              const float* __restrict__ inv,
                                              const float* __restrict__ fmap,
                                              float* __restrict__ out,
                                              int C, int HW) {
    __shared__ float pl[40][CHUNK];
    __shared__ float fl[32][CHUNK + 1];
    int b  = blockIdx.z;
    int kb = blockIdx.y * 40;
    int c0 = blockIdx.x * 32;
    int tid = threadIdx.x;
    int c_l = tid & 31;
    int k_l = (tid >> 5) * 5;
    const float* fb = fmap + (size_t)b * C * HW;
    float acc[5] = {};
    for (int hw0 = 0; hw0 < HW; hw0 += CHUNK) {
        for (int idx = tid; idx < 40 * CHUNK; idx += 256) {
            int r = idx / CHUNK, cc = idx - r * CHUNK;
            int hw = hw0 + cc;
            pl[r][cc] = (hw < HW) ? p[((size_t)b * K_CLS + kb + r) * HW + hw] : 0.f;
        }
        for (int idx = tid; idx < 32 * CHUNK; idx += 256) {
            int r = idx / CHUNK, cc = idx - r * CHUNK;
            int hw = hw0 + cc;
            fl[r][cc] = (hw < HW) ? fb[(size_t)(c0 + r) * HW + hw] : 0.f;
        }
        __syncthreads();
#pragma unroll 4
        for (int j = 0; j < CHUNK; ++j) {
            float fv = fl[c_l][j];
#pragma unroll
            for (int t = 0; t < 5; ++t) acc[t] += pl[k_l + t][j] * fv;
        }
        __syncthreads();
    }
#pragma unroll
    for (int t = 0; t < 5; ++t) {
        int k = kb + k_l + t;
        out[((size_t)b * K_CLS + k) * C + c0 + c_l] = acc[t] * inv[b * K_CLS + k];
    }
}

// ---------------------------------------------------------------------------
extern "C" void kernel_launch(void* const* d_in, const int* in_sizes, int n_in,
                              void* d_out, int out_size, void* d_ws, size_t ws_size,
                              hipStream_t stream) {
    const float* fmap3 = (const float*)d_in[1];
    const float* fmap4 = (const float*)d_in[2];
    const float* word  = (const float*)d_in[3];
    const float* W1_3  = (const float*)d_in[4];
    const float* W2_3  = (const float*)d_in[5];
    const float* W3_3  = (const float*)d_in[6];
    const float* Wa_3  = (const float*)d_in[8];
    const float* W1_4  = (const float*)d_in[10];
    const float* W2_4  = (const float*)d_in[11];
    const float* W3_4  = (const float*)d_in[12];
    const float* Wa_4  = (const float*)d_in[14];
    float* out = (float*)d_out;

    float* ws = (float*)d_ws;
    size_t off = 0;
    float* fw3  = ws + off; off += (size_t)3136 * 512;
    float* fd3  = ws + off; off += (size_t)80 * 512;
    float* v3   = ws + off; off += 512;
    float* sc3  = ws + off; off += (size_t)4 * 80 * 784;
    float* inv3 = ws + off; off += 320;
    float* fw4  = ws + off; off += (size_t)784 * 1024;
    float* fd4  = ws + off; off += (size_t)80 * 1024;
    float* v4   = ws + off; off += 1024;
    float* sc4  = ws + off; off += (size_t)4 * 80 * 196;
    float* inv4 = ws + off; off += 320;

    // ---- stage 3 branch: C=1024, HW=784, D=512 ----
    k_fd<<<(80 * 512 + 255) / 256, 256, 0, stream>>>(word, W2_3, fd3, 512);
    k_v<<<2, 256, 0, stream>>>(Wa_3, W3_3, v3, 512);
    k_fw<<<dim3(512 / 64, (784 + 63) / 64, 4), 256, 0, stream>>>(fmap3, W1_3, fw3, 1024, 784, 512);
    k_score<<<4 * 784, 320, 0, stream>>>(fw3, fd3, v3, sc3, 512, 784);
    k_softmax<<<4 * 80, 256, 0, stream>>>(sc3, inv3, 784);
    k_pool<<<dim3(1024 / 32, 2, 4), 256, 0, stream>>>(sc3, inv3, fmap3, out, 1024, 784);

    // ---- stage 4 branch: C=2048, HW=196, D=1024 ----
    k_fd<<<(80 * 1024 + 255) / 256, 256, 0, stream>>>(word, W2_4, fd4, 1024);
    k_v<<<4, 256, 0, stream>>>(Wa_4, W3_4, v4, 1024);
    k_fw<<<dim3(1024 / 64, (196 + 63) / 64, 4), 256, 0, stream>>>(fmap4, W1_4, fw4, 2048, 196, 1024);
    k_score<<<4 * 196, 320, 0, stream>>>(fw4, fd4, v4, sc4, 1024, 196);
    k_softmax<<<4 * 80, 256, 0, stream>>>(sc4, inv4, 196);
    k_pool<<<dim3(2048 / 32, 2, 4), 256, 0, stream>>>(sc4, inv4, fmap4, out + (size_t)4 * 80 * 1024, 2048, 196);
}

// Round 3
// 583.103 us; speedup vs baseline: 2.0151x; 2.0151x over previous
//
#include <hip/hip_runtime.h>

#define K_CLS 80
#define WDIM  300

typedef __attribute__((ext_vector_type(8))) short s16x8;
typedef __attribute__((ext_vector_type(4))) float f32x4;

__device__ inline unsigned short f2bf(float x) {
    unsigned int u = __builtin_bit_cast(unsigned int, x);
    unsigned int r = (u + 0x7fffu + ((u >> 16) & 1u)) >> 16;
    return (unsigned short)r;
}

// ---------------------------------------------------------------------------
// fd[k][d] = (sum_w word[k,w] * W2[d,w]) * 2*log2(e)
// ---------------------------------------------------------------------------
__global__ __launch_bounds__(256) void k_fd(const float* __restrict__ word,
                                            const float* __restrict__ W2,
                                            float* __restrict__ fd, int D) {
    int idx = blockIdx.x * blockDim.x + threadIdx.x;
    if (idx >= K_CLS * D) return;
    int k = idx / D;
    int d = idx - k * D;
    const float4* wr = (const float4*)(word + (size_t)k * WDIM);
    const float4* w2 = (const float4*)(W2 + (size_t)d * WDIM);
    float acc = 0.f;
#pragma unroll 5
    for (int j = 0; j < WDIM / 4; ++j) {
        float4 a = wr[j], b = w2[j];
        acc += a.x * b.x + a.y * b.y + a.z * b.z + a.w * b.w;
    }
    fd[idx] = acc * 2.885390081777927f;
}

// ---------------------------------------------------------------------------
// v[d] = sum_e Wa[e] * W3[e,d] — 64 d per block, 4 e-groups, LDS reduce
// ---------------------------------------------------------------------------
__global__ __launch_bounds__(256) void k_v(const float* __restrict__ Wa,
                                           const float* __restrict__ W3,
                                           float* __restrict__ v, int D) {
    __shared__ float red[4][64];
    int d0 = blockIdx.x * 64;
    int t = threadIdx.x;
    int dl = t & 63, eg = t >> 6;
    float acc = 0.f;
    for (int e = eg; e < D; e += 4)
        acc += Wa[e] * W3[(size_t)e * D + d0 + dl];
    red[eg][dl] = acc;
    __syncthreads();
    if (t < 64) v[d0 + t] = red[0][t] + red[1][t] + red[2][t] + red[3][t];
}

// ---------------------------------------------------------------------------
// fw[b*HW+hw][d] = sum_c fmap[b][c][hw] * W1[d][c]   -- bf16 MFMA GEMM
// BM=64 (hw), BN=128 (d), BK=32 (c). 256 thr = 4 waves (2m x 2n),
// wave = 32m x 64d = 2x4 frags of 16x16x32.
// A_lds[m][c], B_lds[d][c], row stride 40 bf16 (80 B, conflict-free-ish).
// ---------------------------------------------------------------------------
__global__ __launch_bounds__(256) void k_fw_mfma(const float* __restrict__ fmap,
                                                 const float* __restrict__ W1,
                                                 float* __restrict__ fw,
                                                 int C, int HW, int D) {
    __shared__ short Al[64 * 40];
    __shared__ short Bl[128 * 40];
    int b  = blockIdx.z;
    int m0 = blockIdx.y * 64;
    int d0 = blockIdx.x * 128;
    int tid = threadIdx.x;
    int wave = tid >> 6, lane = tid & 63;
    int wr = wave & 1, wc = wave >> 1;
    const float* fb = fmap + (size_t)b * C * HW;

    int am  = tid & 63;          // m (=hw) index for A staging
    int ac0 = (tid >> 6) * 8;    // 8 c per thread
    int bd  = tid >> 1;          // d row for B staging
    int bc0 = (tid & 1) * 16;    // 16 c per thread

    int hwA = m0 + am;
    bool okA = hwA < HW;

    f32x4 acc[2][4];
#pragma unroll
    for (int i = 0; i < 2; ++i)
#pragma unroll
        for (int j = 0; j < 4; ++j) acc[i][j] = (f32x4){0.f, 0.f, 0.f, 0.f};

    for (int k0 = 0; k0 < C; k0 += 32) {
        // --- stage A (transpose c-major global -> [m][c] LDS) ---
        s16x8 apk;
#pragma unroll
        for (int i = 0; i < 8; ++i) {
            float x = okA ? fb[(size_t)(k0 + ac0 + i) * HW + hwA] : 0.f;
            apk[i] = (short)f2bf(x);
        }
        *(s16x8*)&Al[am * 40 + ac0] = apk;
        // --- stage B: W1 row-major, 16 consecutive c ---
        const float4* wsrc = (const float4*)(W1 + (size_t)(d0 + bd) * C + k0 + bc0);
        s16x8 bpk0, bpk1;
#pragma unroll
        for (int q = 0; q < 2; ++q) {
            float4 w4 = wsrc[q * 2], w5 = wsrc[q * 2 + 1];
            s16x8& dst = q ? bpk1 : bpk0;
            dst[0] = (short)f2bf(w4.x); dst[1] = (short)f2bf(w4.y);
            dst[2] = (short)f2bf(w4.z); dst[3] = (short)f2bf(w4.w);
            dst[4] = (short)f2bf(w5.x); dst[5] = (short)f2bf(w5.y);
            dst[6] = (short)f2bf(w5.z); dst[7] = (short)f2bf(w5.w);
        }
        *(s16x8*)&Bl[bd * 40 + bc0] = bpk0;
        *(s16x8*)&Bl[bd * 40 + bc0 + 8] = bpk1;
        __syncthreads();

        int ko = (lane >> 4) * 8;
        s16x8 afr[2], bfr[4];
#pragma unroll
        for (int mr = 0; mr < 2; ++mr)
            afr[mr] = *(s16x8*)&Al[(wr * 32 + mr * 16 + (lane & 15)) * 40 + ko];
#pragma unroll
        for (int nr = 0; nr < 4; ++nr)
            bfr[nr] = *(s16x8*)&Bl[(wc * 64 + nr * 16 + (lane & 15)) * 40 + ko];
#pragma unroll
        for (int mr = 0; mr < 2; ++mr)
#pragma unroll
            for (int nr = 0; nr < 4; ++nr)
                acc[mr][nr] = __builtin_amdgcn_mfma_f32_16x16x32_bf16(
                    afr[mr], bfr[nr], acc[mr][nr], 0, 0, 0);
        __syncthreads();
    }

    int row4 = (lane >> 4) * 4, col = lane & 15;
#pragma unroll
    for (int mr = 0; mr < 2; ++mr) {
#pragma unroll
        for (int j = 0; j < 4; ++j) {
            int mm = m0 + wr * 32 + mr * 16 + row4 + j;
            if (mm < HW) {
#pragma unroll
                for (int nr = 0; nr < 4; ++nr) {
                    int dd = d0 + wc * 64 + nr * 16 + col;
                    fw[((size_t)b * HW + mm) * D + dd] = acc[mr][nr][j];
                }
            }
        }
    }
}

// ---------------------------------------------------------------------------
// score[b][k][hw] = -2 * sum_d v[d] * rcp(exp2(fw[m,d]*fd2[k,d]) + 1)
// fw row + v staged in LDS (broadcast reads); 4 independent accumulators.
// ---------------------------------------------------------------------------
__global__ __launch_bounds__(320) void k_score(const float* __restrict__ fw,
                                               const float* __restrict__ fd,
                                               const float* __restrict__ v,
                                               float* __restrict__ score,
                                               int D, int HW) {
    __shared__ float fwl[1024];
    __shared__ float vl[1024];
    int m = blockIdx.x;
    int b = m / HW, hw = m - b * HW;
    int tid = threadIdx.x;
    const float* fwg = fw + (size_t)m * D;
    for (int i = tid; i < D; i += 320) {
        fwl[i] = fwg[i];
        vl[i] = v[i];
    }
    __syncthreads();
    int wave = tid >> 6, lane = tid & 63;
    int kk = lane >> 2, ds = lane & 3;
    int k = wave * 16 + kk;
    int DS = D >> 2;
    const float4* fdp = (const float4*)(fd + (size_t)k * D + ds * DS);
    const float4* fwp = (const float4*)(fwl + ds * DS);
    const float4* vp  = (const float4*)(vl + ds * DS);
    float a0 = 0.f, a1 = 0.f, a2 = 0.f, a3 = 0.f;
    int n4 = DS >> 2;  // 32 (s3) or 64 (s4), both %4==0
    for (int j = 0; j < n4; j += 4) {
        float4 f0 = fdp[j], f1 = fdp[j + 1], f2 = fdp[j + 2], f3 = fdp[j + 3];
        float4 w0 = fwp[j], w1 = fwp[j + 1], w2 = fwp[j + 2], w3 = fwp[j + 3];
        float4 v0 = vp[j], v1 = vp[j + 1], v2 = vp[j + 2], v3 = vp[j + 3];
        a0 += v0.x * __builtin_amdgcn_rcpf(__builtin_amdgcn_exp2f(w0.x * f0.x) + 1.f)
            + v0.y * __builtin_amdgcn_rcpf(__builtin_amdgcn_exp2f(w0.y * f0.y) + 1.f)
            + v0.z * __builtin_amdgcn_rcpf(__builtin_amdgcn_exp2f(w0.z * f0.z) + 1.f)
            + v0.w * __builtin_amdgcn_rcpf(__builtin_amdgcn_exp2f(w0.w * f0.w) + 1.f);
        a1 += v1.x * __builtin_amdgcn_rcpf(__builtin_amdgcn_exp2f(w1.x * f1.x) + 1.f)
            + v1.y * __builtin_amdgcn_rcpf(__builtin_amdgcn_exp2f(w1.y * f1.y) + 1.f)
            + v1.z * __builtin_amdgcn_rcpf(__builtin_amdgcn_exp2f(w1.z * f1.z) + 1.f)
            + v1.w * __builtin_amdgcn_rcpf(__builtin_amdgcn_exp2f(w1.w * f1.w) + 1.f);
        a2 += v2.x * __builtin_amdgcn_rcpf(__builtin_amdgcn_exp2f(w2.x * f2.x) + 1.f)
            + v2.y * __builtin_amdgcn_rcpf(__builtin_amdgcn_exp2f(w2.y * f2.y) + 1.f)
            + v2.z * __builtin_amdgcn_rcpf(__builtin_amdgcn_exp2f(w2.z * f2.z) + 1.f)
            + v2.w * __builtin_amdgcn_rcpf(__builtin_amdgcn_exp2f(w2.w * f2.w) + 1.f);
        a3 += v3.x * __builtin_amdgcn_rcpf(__builtin_amdgcn_exp2f(w3.x * f3.x) + 1.f)
            + v3.y * __builtin_amdgcn_rcpf(__builtin_amdgcn_exp2f(w3.y * f3.y) + 1.f)
            + v3.z * __builtin_amdgcn_rcpf(__builtin_amdgcn_exp2f(w3.z * f3.z) + 1.f)
            + v3.w * __builtin_amdgcn_rcpf(__builtin_amdgcn_exp2f(w3.w * f3.w) + 1.f);
    }
    float acc = (a0 + a1) + (a2 + a3);
    acc += __shfl_xor(acc, 1);
    acc += __shfl_xor(acc, 2);
    if (ds == 0) score[((size_t)b * K_CLS + k) * HW + hw] = -2.0f * acc;
}

// ---------------------------------------------------------------------------
// per (b,k): p = exp(score - max); inv = 1/sum(p). In-place.
// ---------------------------------------------------------------------------
__global__ __launch_bounds__(256) void k_softmax(float* __restrict__ score,
                                                 float* __restrict__ inv, int HW) {
    __shared__ float redm[4];
    __shared__ float reds[4];
    int bk = blockIdx.x;
    float* row = score + (size_t)bk * HW;
    int tid = threadIdx.x, lane = tid & 63, wave = tid >> 6;
    float mx = -1e30f;
    for (int i = tid; i < HW; i += 256) mx = fmaxf(mx, row[i]);
#pragma unroll
    for (int o = 32; o >= 1; o >>= 1) mx = fmaxf(mx, __shfl_xor(mx, o));
    if (lane == 0) redm[wave] = mx;
    __syncthreads();
    mx = fmaxf(fmaxf(redm[0], redm[1]), fmaxf(redm[2], redm[3]));
    float sum = 0.f;
    for (int i = tid; i < HW; i += 256) {
        float e = __builtin_amdgcn_exp2f((row[i] - mx) * 1.4426950408889634f);
        row[i] = e;
        sum += e;
    }
#pragma unroll
    for (int o = 32; o >= 1; o >>= 1) sum += __shfl_xor(sum, o);
    if (lane == 0) reds[wave] = sum;
    __syncthreads();
    if (tid == 0) inv[bk] = 1.0f / (reds[0] + reds[1] + reds[2] + reds[3]);
}

// ---------------------------------------------------------------------------
// out[b][k][c] = inv[b,k] * sum_hw p[b][k][hw] * fmap[b][c][hw]
// ---------------------------------------------------------------------------
#define CHUNK 128
__global__ __launch_bounds__(256) void k_pool(const float* __restrict__ p,
                                              const float* __restrict__ inv,
                                              const float* __restrict__ fmap,
                                              float* __restrict__ out,
                                              int C, int HW) {
    __shared__ float pl[40][CHUNK];
    __shared__ float fl[32][CHUNK + 1];
    int b  = blockIdx.z;
    int kb = blockIdx.y * 40;
    int c0 = blockIdx.x * 32;
    int tid = threadIdx.x;
    int c_l = tid & 31;
    int k_l = (tid >> 5) * 5;
    const float* fb = fmap + (size_t)b * C * HW;
    float acc[5] = {};
    for (int hw0 = 0; hw0 < HW; hw0 += CHUNK) {
        for (int idx = tid; idx < 40 * CHUNK; idx += 256) {
            int r = idx / CHUNK, cc = idx - r * CHUNK;
            int hw = hw0 + cc;
            pl[r][cc] = (hw < HW) ? p[((size_t)b * K_CLS + kb + r) * HW + hw] : 0.f;
        }
        for (int idx = tid; idx < 32 * CHUNK; idx += 256) {
            int r = idx / CHUNK, cc = idx - r * CHUNK;
            int hw = hw0 + cc;
            fl[r][cc] = (hw < HW) ? fb[(size_t)(c0 + r) * HW + hw] : 0.f;
        }
        __syncthreads();
#pragma unroll 4
        for (int j = 0; j < CHUNK; ++j) {
            float fv = fl[c_l][j];
#pragma unroll
            for (int t = 0; t < 5; ++t) acc[t] += pl[k_l + t][j] * fv;
        }
        __syncthreads();
    }
#pragma unroll
    for (int t = 0; t < 5; ++t) {
        int k = kb + k_l + t;
        out[((size_t)b * K_CLS + k) * C + c0 + c_l] = acc[t] * inv[b * K_CLS + k];
    }
}

// ---------------------------------------------------------------------------
extern "C" void kernel_launch(void* const* d_in, const int* in_sizes, int n_in,
                              void* d_out, int out_size, void* d_ws, size_t ws_size,
                              hipStream_t stream) {
    const float* fmap3 = (const float*)d_in[1];
    const float* fmap4 = (const float*)d_in[2];
    const float* word  = (const float*)d_in[3];
    const float* W1_3  = (const float*)d_in[4];
    const float* W2_3  = (const float*)d_in[5];
    const float* W3_3  = (const float*)d_in[6];
    const float* Wa_3  = (const float*)d_in[8];
    const float* W1_4  = (const float*)d_in[10];
    const float* W2_4  = (const float*)d_in[11];
    const float* W3_4  = (const float*)d_in[12];
    const float* Wa_4  = (const float*)d_in[14];
    float* out = (float*)d_out;

    float* ws = (float*)d_ws;
    size_t off = 0;
    float* fw3  = ws + off; off += (size_t)3136 * 512;
    float* fd3  = ws + off; off += (size_t)80 * 512;
    float* v3   = ws + off; off += 512;
    float* sc3  = ws + off; off += (size_t)4 * 80 * 784;
    float* inv3 = ws + off; off += 320;
    float* fw4  = ws + off; off += (size_t)784 * 1024;
    float* fd4  = ws + off; off += (size_t)80 * 1024;
    float* v4   = ws + off; off += 1024;
    float* sc4  = ws + off; off += (size_t)4 * 80 * 196;
    float* inv4 = ws + off; off += 320;

    // ---- stage 3 branch: C=1024, HW=784, D=512 ----
    k_fd<<<(80 * 512 + 255) / 256, 256, 0, stream>>>(word, W2_3, fd3, 512);
    k_v<<<512 / 64, 256, 0, stream>>>(Wa_3, W3_3, v3, 512);
    k_fw_mfma<<<dim3(512 / 128, (784 + 63) / 64, 4), 256, 0, stream>>>(fmap3, W1_3, fw3, 1024, 784, 512);
    k_score<<<4 * 784, 320, 0, stream>>>(fw3, fd3, v3, sc3, 512, 784);
    k_softmax<<<4 * 80, 256, 0, stream>>>(sc3, inv3, 784);
    k_pool<<<dim3(1024 / 32, 2, 4), 256, 0, stream>>>(sc3, inv3, fmap3, out, 1024, 784);

    // ---- stage 4 branch: C=2048, HW=196, D=1024 ----
    k_fd<<<(80 * 1024 + 255) / 256, 256, 0, stream>>>(word, W2_4, fd4, 1024);
    k_v<<<1024 / 64, 256, 0, stream>>>(Wa_4, W3_4, v4, 1024);
    k_fw_mfma<<<dim3(1024 / 128, (196 + 63) / 64, 4), 256, 0, stream>>>(fmap4, W1_4, fw4, 2048, 196, 1024);
    k_score<<<4 * 196, 320, 0, stream>>>(fw4, fd4, v4, sc4, 1024, 196);
    k_softmax<<<4 * 80, 256, 0, stream>>>(sc4, inv4, 196);
    k_pool<<<dim3(2048 / 32, 2, 4), 256, 0, stream>>>(sc4, inv4, fmap4, out + (size_t)4 * 80 * 1024, 2048, 196);
}

// Round 4
// 354.447 us; speedup vs baseline: 3.3150x; 1.6451x over previous
//
#include <hip/hip_runtime.h>

#define K_CLS 80
#define WDIM  300

typedef __attribute__((ext_vector_type(8))) short s16x8;
typedef __attribute__((ext_vector_type(4))) float f32x4;

__device__ inline unsigned short f2bf(float x) {
    unsigned int u = __builtin_bit_cast(unsigned int, x);
    unsigned int r = (u + 0x7fffu + ((u >> 16) & 1u)) >> 16;
    return (unsigned short)r;
}

// ---------------------------------------------------------------------------
// Fused small kernel:
//   blocks [0,160)   : fd3[k][d] = (word[k,:]·W2_3[d,:]) * 2log2e   (D=512)
//   blocks [160,480) : fd4 (D=1024)
//   blocks [480,488) : v3[d] = Wa3·W3_3[:,d]  (ILP-8)
//   blocks [488,504) : v4
// ---------------------------------------------------------------------------
__global__ __launch_bounds__(256) void k_small(
    const float* __restrict__ word,
    const float* __restrict__ W23, float* __restrict__ fd3,
    const float* __restrict__ W24, float* __restrict__ fd4,
    const float* __restrict__ Wa3, const float* __restrict__ W33, float* __restrict__ v3,
    const float* __restrict__ Wa4, const float* __restrict__ W34, float* __restrict__ v4) {
    __shared__ float red[4][64];
    int bid = blockIdx.x;
    int t = threadIdx.x;
    if (bid < 480) {
        // ---- fd part ----
        const float* W2; float* fd; int D, base;
        if (bid < 160) { W2 = W23; fd = fd3; D = 512; base = bid; }
        else           { W2 = W24; fd = fd4; D = 1024; base = bid - 160; }
        int idx = base * 256 + t;
        int k = idx / D;
        int d = idx - k * D;
        const float4* wr = (const float4*)(word + (size_t)k * WDIM);
        const float4* w2 = (const float4*)(W2 + (size_t)d * WDIM);
        float acc = 0.f;
#pragma unroll 5
        for (int j = 0; j < WDIM / 4; ++j) {
            float4 a = wr[j], b = w2[j];
            acc += a.x * b.x + a.y * b.y + a.z * b.z + a.w * b.w;
        }
        fd[idx] = acc * 2.885390081777927f;  // 2*log2(e)
    } else {
        // ---- v part ----
        const float* Wa; const float* W3; float* v; int D, vblk;
        if (bid < 488) { Wa = Wa3; W3 = W33; v = v3; D = 512; vblk = bid - 480; }
        else           { Wa = Wa4; W3 = W34; v = v4; D = 1024; vblk = bid - 488; }
        int d0 = vblk * 64;
        int dl = t & 63, eg = t >> 6;
        float a[8] = {};
        int nIt = D >> 5;
        for (int i = 0; i < nIt; ++i) {
            int e0 = eg + 32 * i;
#pragma unroll
            for (int j = 0; j < 8; ++j)
                a[j] = fmaf(Wa[e0 + 4 * j], W3[(size_t)(e0 + 4 * j) * D + d0 + dl], a[j]);
        }
        float s = ((a[0] + a[1]) + (a[2] + a[3])) + ((a[4] + a[5]) + (a[6] + a[7]));
        red[eg][dl] = s;
        __syncthreads();
        if (t < 64) v[d0 + t] = red[0][t] + red[1][t] + red[2][t] + red[3][t];
    }
}

// ---------------------------------------------------------------------------
// fw[b*HW+hw][d] = sum_c fmap[b][c][hw] * W1[d][c]   -- bf16 MFMA GEMM
// Fused s3+s4. BM=64(hw), BN=64(d), BK=32(c), 4 waves, wave = 16m x 64d.
// Double-buffered LDS + register prefetch of the next K-tile.
//   s3: blocks [0,416):  C=1024 HW=784 D=512  (8 d-blk x 13 hw-blk x 4 b)
//   s4: blocks [416,672): C=2048 HW=196 D=1024 (16 x 4 x 4)
// ---------------------------------------------------------------------------
__global__ __launch_bounds__(256) void k_fw(
    const float* __restrict__ fmap3, const float* __restrict__ W13, float* __restrict__ fw3,
    const float* __restrict__ fmap4, const float* __restrict__ W14, float* __restrict__ fw4) {
    __shared__ short Al[2][64 * 40];
    __shared__ short Bl[2][64 * 40];
    int gid = blockIdx.x;
    const float *fmap, *W1; float* fw; int C, HW, D, dnb, hwnb;
    if (gid < 416) { fmap = fmap3; W1 = W13; fw = fw3; C = 1024; HW = 784; D = 512;  dnb = 8;  hwnb = 13; }
    else { gid -= 416; fmap = fmap4; W1 = W14; fw = fw4; C = 2048; HW = 196; D = 1024; dnb = 16; hwnb = 4; }
    int dblk = gid % dnb; gid /= dnb;
    int hwblk = gid % hwnb;
    int b = gid / hwnb;
    int m0 = hwblk * 64, d0 = dblk * 64;
    int tid = threadIdx.x, wave = tid >> 6, lane = tid & 63;
    const float* fb = fmap + (size_t)b * C * HW;

    int am = tid & 63, ac0 = (tid >> 6) * 8;   // A: m=am, 8 c's starting ac0
    int bd = tid >> 2, bc0 = (tid & 3) * 8;    // B: d-row bd, 8 c's starting bc0
    int hwA = m0 + am;
    bool okA = hwA < HW;
    const float* aptr = fb + (size_t)ac0 * HW + (okA ? hwA : 0);
    const float* bptr = W1 + (size_t)(d0 + bd) * C + bc0;

    float ar[8];
    float4 br0, br1;
#pragma unroll
    for (int i = 0; i < 8; ++i) ar[i] = okA ? aptr[(size_t)i * HW] : 0.f;
    br0 = *(const float4*)(bptr);
    br1 = *(const float4*)(bptr + 4);

    f32x4 acc[4];
#pragma unroll
    for (int nr = 0; nr < 4; ++nr) acc[nr] = (f32x4){0.f, 0.f, 0.f, 0.f};

    // convert & write helper (buf), from ar/br0/br1
#define CW(bufi)                                                       \
    {                                                                  \
        s16x8 ap;                                                      \
        _Pragma("unroll") for (int i = 0; i < 8; ++i) ap[i] = (short)f2bf(ar[i]); \
        *(s16x8*)&Al[bufi][am * 40 + ac0] = ap;                        \
        s16x8 bp;                                                      \
        bp[0] = (short)f2bf(br0.x); bp[1] = (short)f2bf(br0.y);        \
        bp[2] = (short)f2bf(br0.z); bp[3] = (short)f2bf(br0.w);        \
        bp[4] = (short)f2bf(br1.x); bp[5] = (short)f2bf(br1.y);        \
        bp[6] = (short)f2bf(br1.z); bp[7] = (short)f2bf(br1.w);        \
        *(s16x8*)&Bl[bufi][bd * 40 + bc0] = bp;                        \
    }

    CW(0);
    __syncthreads();

    int NS = C >> 5;
    int ko = (lane >> 4) * 8, rr = lane & 15;
    for (int s = 0; s < NS; ++s) {
        if (s + 1 < NS) {
            int nk = (s + 1) * 32;
            const float* ap2 = aptr + (size_t)nk * HW;
#pragma unroll
            for (int i = 0; i < 8; ++i) ar[i] = okA ? ap2[(size_t)i * HW] : 0.f;
            br0 = *(const float4*)(bptr + nk);
            br1 = *(const float4*)(bptr + nk + 4);
        }
        int buf = s & 1;
        s16x8 afr = *(s16x8*)&Al[buf][(wave * 16 + rr) * 40 + ko];
        s16x8 bfr[4];
#pragma unroll
        for (int nr = 0; nr < 4; ++nr)
            bfr[nr] = *(s16x8*)&Bl[buf][(nr * 16 + rr) * 40 + ko];
#pragma unroll
        for (int nr = 0; nr < 4; ++nr)
            acc[nr] = __builtin_amdgcn_mfma_f32_16x16x32_bf16(afr, bfr[nr], acc[nr], 0, 0, 0);
        if (s + 1 < NS) CW(buf ^ 1);
        __syncthreads();
    }

    int row4 = (lane >> 4) * 4, col = lane & 15;
#pragma unroll
    for (int j = 0; j < 4; ++j) {
        int mm = m0 + wave * 16 + row4 + j;
        if (mm < HW) {
#pragma unroll
            for (int nr = 0; nr < 4; ++nr)
                fw[((size_t)b * HW + mm) * D + d0 + nr * 16 + col] = acc[nr][j];
        }
    }
#undef CW
}

// ---------------------------------------------------------------------------
// p[b][k][hw] = exp(-2 * sum_d v[d] * rcp(exp2(fw[m,d]*fd2[k,d]) + 1))
// (unnormalized softmax numerator; scores bounded so no max-subtraction needed)
// Block covers 4 hw rows of one b; 5 waves; 4 lanes per k split d in quarters.
//   s3: blocks [0,784): D=512 HW=784; s4: [784,980): D=1024 HW=196
// ---------------------------------------------------------------------------
__global__ __launch_bounds__(320) void k_score(
    const float* __restrict__ fw3, const float* __restrict__ fd3,
    const float* __restrict__ v3, float* __restrict__ p3,
    const float* __restrict__ fw4, const float* __restrict__ fd4,
    const float* __restrict__ v4, float* __restrict__ p4) {
    __shared__ float fwl[4][1024];
    __shared__ float vl[1024];
    int bid = blockIdx.x;
    const float *fw, *fd, *v; float* p; int D, HW;
    if (bid < 784) { fw = fw3; fd = fd3; v = v3; p = p3; D = 512; HW = 784; }
    else { bid -= 784; fw = fw4; fd = fd4; v = v4; p = p4; D = 1024; HW = 196; }
    int nt = HW >> 2;
    int b = bid / nt, m0 = (bid - b * nt) * 4;
    int tid = threadIdx.x;
    const float* fwg = fw + ((size_t)b * HW + m0) * D;
    for (int i = tid; i < D; i += 320) {
        vl[i] = v[i];
#pragma unroll
        for (int t2 = 0; t2 < 4; ++t2) fwl[t2][i] = fwg[(size_t)t2 * D + i];
    }
    __syncthreads();
    int wave = tid >> 6, lane = tid & 63;
    int kk = lane >> 2, ds = lane & 3;
    int k = wave * 16 + kk;
    int DS = D >> 2;
    const float4* fdp = (const float4*)(fd + (size_t)k * D + ds * DS);
    const float4* vp  = (const float4*)(vl + ds * DS);
    int n4 = DS >> 2;
    for (int t = 0; t < 4; ++t) {
        const float4* fwp = (const float4*)(&fwl[t][ds * DS]);
        float a0 = 0.f, a1 = 0.f, a2 = 0.f, a3 = 0.f;
        for (int j = 0; j < n4; j += 4) {
            float4 f0 = fdp[j], f1 = fdp[j + 1], f2 = fdp[j + 2], f3 = fdp[j + 3];
            float4 w0 = fwp[j], w1 = fwp[j + 1], w2 = fwp[j + 2], w3 = fwp[j + 3];
            float4 v0 = vp[j], v1 = vp[j + 1], v2 = vp[j + 2], v3_ = vp[j + 3];
            a0 += v0.x * __builtin_amdgcn_rcpf(__builtin_amdgcn_exp2f(w0.x * f0.x) + 1.f)
                + v0.y * __builtin_amdgcn_rcpf(__builtin_amdgcn_exp2f(w0.y * f0.y) + 1.f)
                + v0.z * __builtin_amdgcn_rcpf(__builtin_amdgcn_exp2f(w0.z * f0.z) + 1.f)
                + v0.w * __builtin_amdgcn_rcpf(__builtin_amdgcn_exp2f(w0.w * f0.w) + 1.f);
            a1 += v1.x * __builtin_amdgcn_rcpf(__builtin_amdgcn_exp2f(w1.x * f1.x) + 1.f)
                + v1.y * __builtin_amdgcn_rcpf(__builtin_amdgcn_exp2f(w1.y * f1.y) + 1.f)
                + v1.z * __builtin_amdgcn_rcpf(__builtin_amdgcn_exp2f(w1.z * f1.z) + 1.f)
                + v1.w * __builtin_amdgcn_rcpf(__builtin_amdgcn_exp2f(w1.w * f1.w) + 1.f);
            a2 += v2.x * __builtin_amdgcn_rcpf(__builtin_amdgcn_exp2f(w2.x * f2.x) + 1.f)
                + v2.y * __builtin_amdgcn_rcpf(__builtin_amdgcn_exp2f(w2.y * f2.y) + 1.f)
                + v2.z * __builtin_amdgcn_rcpf(__builtin_amdgcn_exp2f(w2.z * f2.z) + 1.f)
                + v2.w * __builtin_amdgcn_rcpf(__builtin_amdgcn_exp2f(w2.w * f2.w) + 1.f);
            a3 += v3_.x * __builtin_amdgcn_rcpf(__builtin_amdgcn_exp2f(w3.x * f3.x) + 1.f)
                + v3_.y * __builtin_amdgcn_rcpf(__builtin_amdgcn_exp2f(w3.y * f3.y) + 1.f)
                + v3_.z * __builtin_amdgcn_rcpf(__builtin_amdgcn_exp2f(w3.z * f3.z) + 1.f)
                + v3_.w * __builtin_amdgcn_rcpf(__builtin_amdgcn_exp2f(w3.w * f3.w) + 1.f);
        }
        float acc = (a0 + a1) + (a2 + a3);
        acc += __shfl_xor(acc, 1);
        acc += __shfl_xor(acc, 2);
        if (ds == 0)
            p[((size_t)b * K_CLS + k) * HW + m0 + t] =
                __builtin_amdgcn_exp2f(acc * -2.885390081777927f);
    }
}

// ---------------------------------------------------------------------------
// out[b][k][c] = (sum_hw p·fmap) / (sum_hw p)   -- psum folded into the sweep
//   s3: blocks [0,256): C=1024 HW=784; s4: [256,768): C=2048 HW=196
// ---------------------------------------------------------------------------
#define CHUNK 128
__global__ __launch_bounds__(256) void k_pool(
    const float* __restrict__ p3, const float* __restrict__ fmap3,
    const float* __restrict__ p4, const float* __restrict__ fmap4,
    float* __restrict__ out) {
    __shared__ float pl[40][CHUNK];
    __shared__ float fl[32][CHUNK + 1];
    int bid = blockIdx.x;
    const float *p, *fmap; float* o; int C, HW;
    if (bid < 256) { p = p3; fmap = fmap3; o = out; C = 1024; HW = 784; }
    else { bid -= 256; p = p4; fmap = fmap4; o = out + (size_t)4 * K_CLS * 1024; C = 2048; HW = 196; }
    int cnb = C >> 5;
    int c0 = (bid % cnb) * 32; bid /= cnb;
    int kb = (bid & 1) * 40;
    int b = bid >> 1;
    int tid = threadIdx.x;
    int c_l = tid & 31;
    int k_l = (tid >> 5) * 5;
    const float* fb = fmap + (size_t)b * C * HW;
    float acc[5] = {}, ps[5] = {};
    for (int hw0 = 0; hw0 < HW; hw0 += CHUNK) {
        for (int idx = tid; idx < 40 * CHUNK; idx += 256) {
            int r = idx >> 7, cc = idx & (CHUNK - 1);
            int hw = hw0 + cc;
            pl[r][cc] = (hw < HW) ? p[((size_t)b * K_CLS + kb + r) * HW + hw] : 0.f;
        }
        for (int idx = tid; idx < 32 * CHUNK; idx += 256) {
            int r = idx >> 7, cc = idx & (CHUNK - 1);
            int hw = hw0 + cc;
            fl[r][cc] = (hw < HW) ? fb[(size_t)(c0 + r) * HW + hw] : 0.f;
        }
        __syncthreads();
#pragma unroll 4
        for (int j = 0; j < CHUNK; ++j) {
            float fv = fl[c_l][j];
#pragma unroll
            for (int t = 0; t < 5; ++t) {
                float pv = pl[k_l + t][j];
                acc[t] += pv * fv;
                ps[t] += pv;
            }
        }
        __syncthreads();
    }
#pragma unroll
    for (int t = 0; t < 5; ++t) {
        int k = kb + k_l + t;
        o[((size_t)b * K_CLS + k) * C + c0 + c_l] = acc[t] / ps[t];
    }
}

// ---------------------------------------------------------------------------
extern "C" void kernel_launch(void* const* d_in, const int* in_sizes, int n_in,
                              void* d_out, int out_size, void* d_ws, size_t ws_size,
                              hipStream_t stream) {
    const float* fmap3 = (const float*)d_in[1];
    const float* fmap4 = (const float*)d_in[2];
    const float* word  = (const float*)d_in[3];
    const float* W1_3  = (const float*)d_in[4];
    const float* W2_3  = (const float*)d_in[5];
    const float* W3_3  = (const float*)d_in[6];
    const float* Wa_3  = (const float*)d_in[8];
    const float* W1_4  = (const float*)d_in[10];
    const float* W2_4  = (const float*)d_in[11];
    const float* W3_4  = (const float*)d_in[12];
    const float* Wa_4  = (const float*)d_in[14];
    float* out = (float*)d_out;

    float* ws = (float*)d_ws;
    size_t off = 0;
    float* fw3 = ws + off; off += (size_t)3136 * 512;
    float* fd3 = ws + off; off += (size_t)80 * 512;
    float* v3  = ws + off; off += 512;
    float* sc3 = ws + off; off += (size_t)4 * 80 * 784;
    float* fw4 = ws + off; off += (size_t)784 * 1024;
    float* fd4 = ws + off; off += (size_t)80 * 1024;
    float* v4  = ws + off; off += 1024;
    float* sc4 = ws + off; off += (size_t)4 * 80 * 196;

    k_small<<<504, 256, 0, stream>>>(word, W2_3, fd3, W2_4, fd4,
                                     Wa_3, W3_3, v3, Wa_4, W3_4, v4);
    k_fw<<<672, 256, 0, stream>>>(fmap3, W1_3, fw3, fmap4, W1_4, fw4);
    k_score<<<980, 320, 0, stream>>>(fw3, fd3, v3, sc3, fw4, fd4, v4, sc4);
    k_pool<<<768, 256, 0, stream>>>(sc3, fmap3, sc4, fmap4, out);
}

// Round 6
// 315.639 us; speedup vs baseline: 3.7226x; 1.1229x over previous
//
#include <hip/hip_runtime.h>

#define K_CLS 80
#define WDIM  300

typedef __attribute__((ext_vector_type(8))) short s16x8;
typedef __attribute__((ext_vector_type(4))) short s16x4;
typedef __attribute__((ext_vector_type(4))) float f32x4;

__device__ inline unsigned short f2bf(float x) {
    unsigned int u = __builtin_bit_cast(unsigned int, x);
    unsigned int r = (u + 0x7fffu + ((u >> 16) & 1u)) >> 16;
    return (unsigned short)r;
}

__device__ inline float dot4(float4 a, float4 b) {
    return a.x * b.x + a.y * b.y + a.z * b.z + a.w * b.w;
}

// sum_i v_i * sigmoid-ish term; tanh collapsed: rcp(exp2(w*f)+1), f pre-scaled
__device__ inline float t4(float4 wv, float4 fv, float4 vv) {
    return vv.x * __builtin_amdgcn_rcpf(__builtin_amdgcn_exp2f(wv.x * fv.x) + 1.f)
         + vv.y * __builtin_amdgcn_rcpf(__builtin_amdgcn_exp2f(wv.y * fv.y) + 1.f)
         + vv.z * __builtin_amdgcn_rcpf(__builtin_amdgcn_exp2f(wv.z * fv.z) + 1.f)
         + vv.w * __builtin_amdgcn_rcpf(__builtin_amdgcn_exp2f(wv.w * fv.w) + 1.f);
}

// ---------------------------------------------------------------------------
// Fused small kernel:
//   fd: 4 k per thread (word rows L1-broadcast, W2 row read once per 4 k)
//     blocks [0,40):   s3  (kt=bid>>1, dblk=bid&1), D=512
//     blocks [40,120): s4  (kt,dblk of 4), D=1024
//   v[d] = Wa·W3[:,d] with ILP-8:
//     blocks [120,128): v3 ; [128,144): v4
// ---------------------------------------------------------------------------
__global__ __launch_bounds__(256) void k_small(
    const float* __restrict__ word,
    const float* __restrict__ W23, float* __restrict__ fd3,
    const float* __restrict__ W24, float* __restrict__ fd4,
    const float* __restrict__ Wa3, const float* __restrict__ W33, float* __restrict__ v3,
    const float* __restrict__ Wa4, const float* __restrict__ W34, float* __restrict__ v4) {
    __shared__ float red[4][64];
    int bid = blockIdx.x;
    int t = threadIdx.x;
    if (bid < 120) {
        const float* W2; float* fd; int D, kt, dblk;
        if (bid < 40) { W2 = W23; fd = fd3; D = 512; kt = bid >> 1; dblk = bid & 1; }
        else { int i2 = bid - 40; W2 = W24; fd = fd4; D = 1024; kt = i2 >> 2; dblk = i2 & 3; }
        int d = dblk * 256 + t;
        int k0 = kt * 4;
        const float4* w2p = (const float4*)(W2 + (size_t)d * WDIM);
        const float4* wr0 = (const float4*)(word + (size_t)(k0 + 0) * WDIM);
        const float4* wr1 = (const float4*)(word + (size_t)(k0 + 1) * WDIM);
        const float4* wr2 = (const float4*)(word + (size_t)(k0 + 2) * WDIM);
        const float4* wr3 = (const float4*)(word + (size_t)(k0 + 3) * WDIM);
        float a0 = 0.f, a1 = 0.f, a2 = 0.f, a3 = 0.f;
#pragma unroll 5
        for (int j = 0; j < WDIM / 4; ++j) {
            float4 w = w2p[j];
            a0 += dot4(wr0[j], w);
            a1 += dot4(wr1[j], w);
            a2 += dot4(wr2[j], w);
            a3 += dot4(wr3[j], w);
        }
        const float S = 2.885390081777927f;  // 2*log2(e)
        fd[(size_t)(k0 + 0) * D + d] = a0 * S;
        fd[(size_t)(k0 + 1) * D + d] = a1 * S;
        fd[(size_t)(k0 + 2) * D + d] = a2 * S;
        fd[(size_t)(k0 + 3) * D + d] = a3 * S;
    } else {
        const float* Wa; const float* W3; float* v; int D, vblk;
        if (bid < 128) { Wa = Wa3; W3 = W33; v = v3; D = 512; vblk = bid - 120; }
        else           { Wa = Wa4; W3 = W34; v = v4; D = 1024; vblk = bid - 128; }
        int d0 = vblk * 64;
        int dl = t & 63, eg = t >> 6;
        float a[8] = {};
        int nIt = D >> 5;
        for (int i = 0; i < nIt; ++i) {
            int e0 = eg + 32 * i;
#pragma unroll
            for (int j = 0; j < 8; ++j)
                a[j] = fmaf(Wa[e0 + 4 * j], W3[(size_t)(e0 + 4 * j) * D + d0 + dl], a[j]);
        }
        float s = ((a[0] + a[1]) + (a[2] + a[3])) + ((a[4] + a[5]) + (a[6] + a[7]));
        red[eg][dl] = s;
        __syncthreads();
        if (t < 64) v[d0 + t] = red[0][t] + red[1][t] + red[2][t] + red[3][t];
    }
}

// ---------------------------------------------------------------------------
// fw[b*HW+hw][d] = sum_c fmap[b][c][hw] * W1[d][c]   -- bf16 MFMA GEMM
// BM=128(hw), BN=64(d), BK=32(c), 512 thr = 8 waves, wave = 16m x 64d.
// Double-buffered LDS + register prefetch.
//   s3: blocks [0,224):   C=1024 HW=784 D=512  (8 dnb x 7 hwnb x 4 b)
//   s4: blocks [224,352): C=2048 HW=196 D=1024 (16 x 2 x 4)
// ---------------------------------------------------------------------------
__global__ __launch_bounds__(512) void k_fw(
    const float* __restrict__ fmap3, const float* __restrict__ W13, float* __restrict__ fw3,
    const float* __restrict__ fmap4, const float* __restrict__ W14, float* __restrict__ fw4) {
    __shared__ short Al[2][128 * 40];
    __shared__ short Bl[2][64 * 40];
    int gid = blockIdx.x;
    const float *fmap, *W1; float* fw; int C, HW, D, dnb, hwnb;
    if (gid < 224) { fmap = fmap3; W1 = W13; fw = fw3; C = 1024; HW = 784; D = 512;  dnb = 8;  hwnb = 7; }
    else { gid -= 224; fmap = fmap4; W1 = W14; fw = fw4; C = 2048; HW = 196; D = 1024; dnb = 16; hwnb = 2; }
    int dblk = gid % dnb; gid /= dnb;
    int hwblk = gid % hwnb;
    int b = gid / hwnb;
    int m0 = hwblk * 128, d0 = dblk * 64;
    int tid = threadIdx.x, wave = tid >> 6, lane = tid & 63;
    const float* fb = fmap + (size_t)b * C * HW;

    int am = tid & 127, ac0 = (tid >> 7) * 8;  // A: m-row am, 8 c's from ac0
    int bd = tid >> 3, bc0 = (tid & 7) * 4;    // B: d-row bd, 4 c's from bc0
    int hwA = m0 + am;
    bool okA = hwA < HW;
    const float* aptr = fb + (size_t)ac0 * HW + (okA ? hwA : 0);
    const float* bptr = W1 + (size_t)(d0 + bd) * C + bc0;

    float ar[8];
    float4 br;
#pragma unroll
    for (int i = 0; i < 8; ++i) ar[i] = okA ? aptr[(size_t)i * HW] : 0.f;
    br = *(const float4*)bptr;

    f32x4 acc[4];
#pragma unroll
    for (int nr = 0; nr < 4; ++nr) acc[nr] = (f32x4){0.f, 0.f, 0.f, 0.f};

#define CW(bufi)                                                              \
    {                                                                         \
        s16x8 ap;                                                             \
        _Pragma("unroll") for (int i = 0; i < 8; ++i) ap[i] = (short)f2bf(ar[i]); \
        *(s16x8*)&Al[bufi][am * 40 + ac0] = ap;                               \
        s16x4 bp;                                                             \
        bp[0] = (short)f2bf(br.x); bp[1] = (short)f2bf(br.y);                 \
        bp[2] = (short)f2bf(br.z); bp[3] = (short)f2bf(br.w);                 \
        *(s16x4*)&Bl[bufi][bd * 40 + bc0] = bp;                               \
    }

    CW(0);
    __syncthreads();

    int NS = C >> 5;
    int ko = (lane >> 4) * 8, rr = lane & 15;
    for (int s = 0; s < NS; ++s) {
        if (s + 1 < NS) {
            const float* ap2 = aptr + (size_t)(s + 1) * 32 * HW;
#pragma unroll
            for (int i = 0; i < 8; ++i) ar[i] = okA ? ap2[(size_t)i * HW] : 0.f;
            br = *(const float4*)(bptr + (s + 1) * 32);
        }
        int buf = s & 1;
        s16x8 afr = *(s16x8*)&Al[buf][(wave * 16 + rr) * 40 + ko];
        s16x8 bfr[4];
#pragma unroll
        for (int nr = 0; nr < 4; ++nr)
            bfr[nr] = *(s16x8*)&Bl[buf][(nr * 16 + rr) * 40 + ko];
#pragma unroll
        for (int nr = 0; nr < 4; ++nr)
            acc[nr] = __builtin_amdgcn_mfma_f32_16x16x32_bf16(afr, bfr[nr], acc[nr], 0, 0, 0);
        if (s + 1 < NS) CW(buf ^ 1);
        __syncthreads();
    }
#undef CW

    int row4 = (lane >> 4) * 4, col = lane & 15;
#pragma unroll
    for (int j = 0; j < 4; ++j) {
        int mm = m0 + wave * 16 + row4 + j;
        if (mm < HW) {
#pragma unroll
            for (int nr = 0; nr < 4; ++nr)
                fw[((size_t)b * HW + mm) * D + d0 + nr * 16 + col] = acc[nr][j];
        }
    }
}

// ---------------------------------------------------------------------------
// p[b][k][hw] = exp(-2 * sum_d v[d] * rcp(exp2(fw[m,d]*fd2[k,d]) + 1))
// d-interleaved lane partition (conflict-free LDS), fd loaded once per 4 hw.
//   s3: blocks [0,784): D=512 HW=784; s4: [784,980): D=1024 HW=196
// ---------------------------------------------------------------------------
__global__ __launch_bounds__(320) void k_score(
    const float* __restrict__ fw3, const float* __restrict__ fd3,
    const float* __restrict__ v3, float* __restrict__ p3,
    const float* __restrict__ fw4, const float* __restrict__ fd4,
    const float* __restrict__ v4, float* __restrict__ p4) {
    __shared__ float fwl[4][1024];
    __shared__ float vl[1024];
    int bid = blockIdx.x;
    const float *fw, *fd, *v; float* p; int D, HW;
    if (bid < 784) { fw = fw3; fd = fd3; v = v3; p = p3; D = 512; HW = 784; }
    else { bid -= 784; fw = fw4; fd = fd4; v = v4; p = p4; D = 1024; HW = 196; }
    int nt = HW >> 2;
    int b = bid / nt, m0 = (bid - b * nt) * 4;
    int tid = threadIdx.x;
    const float* fwg = fw + ((size_t)b * HW + m0) * D;
    int D4 = D >> 2;
    if (tid < D4) {
        ((float4*)vl)[tid] = ((const float4*)v)[tid];
#pragma unroll
        for (int t = 0; t < 4; ++t)
            ((float4*)fwl[t])[tid] = ((const float4*)(fwg + (size_t)t * D))[tid];
    }
    __syncthreads();
    int wave = tid >> 6, lane = tid & 63;
    int kk = lane >> 2, ds = lane & 3;
    int k = wave * 16 + kk;
    const float4* fdp = (const float4*)(fd + (size_t)k * D);
    const float4* vp  = (const float4*)vl;
    const float4* w0p = (const float4*)fwl[0];
    const float4* w1p = (const float4*)fwl[1];
    const float4* w2p = (const float4*)fwl[2];
    const float4* w3p = (const float4*)fwl[3];
    float acc0 = 0.f, acc1 = 0.f, acc2 = 0.f, acc3 = 0.f;
    int NJ = D >> 4;  // groups of 4 float4-chunks; lane ds owns cj%4==ds
    for (int jj = 0; jj < NJ; jj += 2) {
        int c0 = jj * 4 + ds, c1 = c0 + 4;
        float4 f0 = fdp[c0], f1 = fdp[c1];
        float4 va = vp[c0], vb = vp[c1];
        acc0 += t4(w0p[c0], f0, va) + t4(w0p[c1], f1, vb);
        acc1 += t4(w1p[c0], f0, va) + t4(w1p[c1], f1, vb);
        acc2 += t4(w2p[c0], f0, va) + t4(w2p[c1], f1, vb);
        acc3 += t4(w3p[c0], f0, va) + t4(w3p[c1], f1, vb);
    }
    acc0 += __shfl_xor(acc0, 1); acc0 += __shfl_xor(acc0, 2);
    acc1 += __shfl_xor(acc1, 1); acc1 += __shfl_xor(acc1, 2);
    acc2 += __shfl_xor(acc2, 1); acc2 += __shfl_xor(acc2, 2);
    acc3 += __shfl_xor(acc3, 1); acc3 += __shfl_xor(acc3, 2);
    if (ds == 0) {
        const float S = -2.885390081777927f;  // -2 * log2(e) -> exp2
        float* pr = p + ((size_t)b * K_CLS + k) * HW + m0;
        pr[0] = __builtin_amdgcn_exp2f(acc0 * S);
        pr[1] = __builtin_amdgcn_exp2f(acc1 * S);
        pr[2] = __builtin_amdgcn_exp2f(acc2 * S);
        pr[3] = __builtin_amdgcn_exp2f(acc3 * S);
    }
}

// ---------------------------------------------------------------------------
// out[b][k][c] = (sum_hw p·fmap) / (sum_hw p)
//   s3: blocks [0,256): C=1024 HW=784; s4: [256,768): C=2048 HW=196
// ---------------------------------------------------------------------------
#define CHUNK 128
__global__ __launch_bounds__(256) void k_pool(
    const float* __restrict__ p3, const float* __restrict__ fmap3,
    const float* __restrict__ p4, const float* __restrict__ fmap4,
    float* __restrict__ out) {
    __shared__ float pl[40][CHUNK];
    __shared__ float fl[32][CHUNK + 1];
    int bid = blockIdx.x;
    const float *p, *fmap; float* o; int C, HW;
    if (bid < 256) { p = p3; fmap = fmap3; o = out; C = 1024; HW = 784; }
    else { bid -= 256; p = p4; fmap = fmap4; o = out + (size_t)4 * K_CLS * 1024; C = 2048; HW = 196; }
    int cnb = C >> 5;
    int c0 = (bid % cnb) * 32; bid /= cnb;
    int kb = (bid & 1) * 40;
    int b = bid >> 1;
    int tid = threadIdx.x;
    int c_l = tid & 31;
    int k_l = (tid >> 5) * 5;
    const float* fb = fmap + (size_t)b * C * HW;
    float acc[5] = {}, ps[5] = {};
    for (int hw0 = 0; hw0 < HW; hw0 += CHUNK) {
        for (int idx = tid; idx < 40 * CHUNK; idx += 256) {
            int r = idx >> 7, cc = idx & (CHUNK - 1);
            int hw = hw0 + cc;
            pl[r][cc] = (hw < HW) ? p[((size_t)b * K_CLS + kb + r) * HW + hw] : 0.f;
        }
        for (int idx = tid; idx < 32 * CHUNK; idx += 256) {
            int r = idx >> 7, cc = idx & (CHUNK - 1);
            int hw = hw0 + cc;
            fl[r][cc] = (hw < HW) ? fb[(size_t)(c0 + r) * HW + hw] : 0.f;
        }
        __syncthreads();
#pragma unroll 4
        for (int j = 0; j < CHUNK; ++j) {
            float fv = fl[c_l][j];
#pragma unroll
            for (int t = 0; t < 5; ++t) {
                float pv = pl[k_l + t][j];
                acc[t] += pv * fv;
                ps[t] += pv;
            }
        }
        __syncthreads();
    }
#pragma unroll
    for (int t = 0; t < 5; ++t) {
        int k = kb + k_l + t;
        o[((size_t)b * K_CLS + k) * C + c0 + c_l] = acc[t] / ps[t];
    }
}

// ---------------------------------------------------------------------------
extern "C" void kernel_launch(void* const* d_in, const int* in_sizes, int n_in,
                              void* d_out, int out_size, void* d_ws, size_t ws_size,
                              hipStream_t stream) {
    const float* fmap3 = (const float*)d_in[1];
    const float* fmap4 = (const float*)d_in[2];
    const float* word  = (const float*)d_in[3];
    const float* W1_3  = (const float*)d_in[4];
    const float* W2_3  = (const float*)d_in[5];
    const float* W3_3  = (const float*)d_in[6];
    const float* Wa_3  = (const float*)d_in[8];
    const float* W1_4  = (const float*)d_in[10];
    const float* W2_4  = (const float*)d_in[11];
    const float* W3_4  = (const float*)d_in[12];
    const float* Wa_4  = (const float*)d_in[14];
    float* out = (float*)d_out;

    float* ws = (float*)d_ws;
    size_t off = 0;
    float* fw3 = ws + off; off += (size_t)3136 * 512;
    float* fd3 = ws + off; off += (size_t)80 * 512;
    float* v3  = ws + off; off += 512;
    float* sc3 = ws + off; off += (size_t)4 * 80 * 784;
    float* fw4 = ws + off; off += (size_t)784 * 1024;
    float* fd4 = ws + off; off += (size_t)80 * 1024;
    float* v4  = ws + off; off += 1024;
    float* sc4 = ws + off; off += (size_t)4 * 80 * 196;

    k_small<<<144, 256, 0, stream>>>(word, W2_3, fd3, W2_4, fd4,
                                     Wa_3, W3_3, v3, Wa_4, W3_4, v4);
    k_fw<<<352, 512, 0, stream>>>(fmap3, W1_3, fw3, fmap4, W1_4, fw4);
    k_score<<<980, 320, 0, stream>>>(fw3, fd3, v3, sc3, fw4, fd4, v4, sc4);
    k_pool<<<768, 256, 0, stream>>>(sc3, fmap3, sc4, fmap4, out);
}

// Round 14
// 294.876 us; speedup vs baseline: 3.9847x; 1.0704x over previous
//
#include <hip/hip_runtime.h>

#define K_CLS 80
#define WDIM  300

typedef __attribute__((ext_vector_type(8))) short s16x8;
typedef __attribute__((ext_vector_type(4))) short s16x4;
typedef __attribute__((ext_vector_type(4))) float f32x4;

__device__ inline unsigned short f2bf(float x) {
    unsigned int u = __builtin_bit_cast(unsigned int, x);
    unsigned int r = (u + 0x7fffu + ((u >> 16) & 1u)) >> 16;
    return (unsigned short)r;
}

__device__ inline float dot4(float4 a, float4 b) {
    return a.x * b.x + a.y * b.y + a.z * b.z + a.w * b.w;
}

// sum_i v_i * sigmoid-ish term; tanh collapsed: rcp(exp2(w*f)+1), f pre-scaled
__device__ inline float t4(float4 wv, float4 fv, float4 vv) {
    return vv.x * __builtin_amdgcn_rcpf(__builtin_amdgcn_exp2f(wv.x * fv.x) + 1.f)
         + vv.y * __builtin_amdgcn_rcpf(__builtin_amdgcn_exp2f(wv.y * fv.y) + 1.f)
         + vv.z * __builtin_amdgcn_rcpf(__builtin_amdgcn_exp2f(wv.z * fv.z) + 1.f)
         + vv.w * __builtin_amdgcn_rcpf(__builtin_amdgcn_exp2f(wv.w * fv.w) + 1.f);
}

// ---------------------------------------------------------------------------
// Fused small kernel:
//   fd: 4 k per thread: blocks [0,40): s3 ; [40,120): s4
//   v : blocks [120,128): v3 ; [128,144): v4
//   psum zero-init: block 144
// ---------------------------------------------------------------------------
__global__ __launch_bounds__(256) void k_small(
    const float* __restrict__ word,
    const float* __restrict__ W23, float* __restrict__ fd3,
    const float* __restrict__ W24, float* __restrict__ fd4,
    const float* __restrict__ Wa3, const float* __restrict__ W33, float* __restrict__ v3,
    const float* __restrict__ Wa4, const float* __restrict__ W34, float* __restrict__ v4,
    float* __restrict__ ps3, float* __restrict__ ps4) {
    __shared__ float red[4][64];
    int bid = blockIdx.x;
    int t = threadIdx.x;
    if (bid < 120) {
        const float* W2; float* fd; int D, kt, dblk;
        if (bid < 40) { W2 = W23; fd = fd3; D = 512; kt = bid >> 1; dblk = bid & 1; }
        else { int i2 = bid - 40; W2 = W24; fd = fd4; D = 1024; kt = i2 >> 2; dblk = i2 & 3; }
        int d = dblk * 256 + t;
        int k0 = kt * 4;
        const float4* w2p = (const float4*)(W2 + (size_t)d * WDIM);
        const float4* wr0 = (const float4*)(word + (size_t)(k0 + 0) * WDIM);
        const float4* wr1 = (const float4*)(word + (size_t)(k0 + 1) * WDIM);
        const float4* wr2 = (const float4*)(word + (size_t)(k0 + 2) * WDIM);
        const float4* wr3 = (const float4*)(word + (size_t)(k0 + 3) * WDIM);
        float a0 = 0.f, a1 = 0.f, a2 = 0.f, a3 = 0.f;
#pragma unroll 5
        for (int j = 0; j < WDIM / 4; ++j) {
            float4 w = w2p[j];
            a0 += dot4(wr0[j], w);
            a1 += dot4(wr1[j], w);
            a2 += dot4(wr2[j], w);
            a3 += dot4(wr3[j], w);
        }
        const float S = 2.885390081777927f;  // 2*log2(e)
        fd[(size_t)(k0 + 0) * D + d] = a0 * S;
        fd[(size_t)(k0 + 1) * D + d] = a1 * S;
        fd[(size_t)(k0 + 2) * D + d] = a2 * S;
        fd[(size_t)(k0 + 3) * D + d] = a3 * S;
    } else if (bid < 144) {
        const float* Wa; const float* W3; float* v; int D, vblk;
        if (bid < 128) { Wa = Wa3; W3 = W33; v = v3; D = 512; vblk = bid - 120; }
        else           { Wa = Wa4; W3 = W34; v = v4; D = 1024; vblk = bid - 128; }
        int d0 = vblk * 64;
        int dl = t & 63, eg = t >> 6;
        float a[8] = {};
        int nIt = D >> 5;
        for (int i = 0; i < nIt; ++i) {
            int e0 = eg + 32 * i;
#pragma unroll
            for (int j = 0; j < 8; ++j)
                a[j] = fmaf(Wa[e0 + 4 * j], W3[(size_t)(e0 + 4 * j) * D + d0 + dl], a[j]);
        }
        float s = ((a[0] + a[1]) + (a[2] + a[3])) + ((a[4] + a[5]) + (a[6] + a[7]));
        red[eg][dl] = s;
        __syncthreads();
        if (t < 64) v[d0 + t] = red[0][t] + red[1][t] + red[2][t] + red[3][t];
    } else {
        for (int i = t; i < 4 * K_CLS; i += 256) { ps3[i] = 0.f; ps4[i] = 0.f; }
    }
}

// ---------------------------------------------------------------------------
// fw[b*HW+hw][d] = sum_c fmap[b][c][hw] * W1[d][c]   -- bf16 MFMA GEMM
// BM=128(hw), BN=64(d), BK=32(c), 512 thr = 8 waves, wave = 16m x 64d.
// Double-buffered LDS + register prefetch.
// ---------------------------------------------------------------------------
__global__ __launch_bounds__(512) void k_fw(
    const float* __restrict__ fmap3, const float* __restrict__ W13, float* __restrict__ fw3,
    const float* __restrict__ fmap4, const float* __restrict__ W14, float* __restrict__ fw4) {
    __shared__ short Al[2][128 * 40];
    __shared__ short Bl[2][64 * 40];
    int gid = blockIdx.x;
    const float *fmap, *W1; float* fw; int C, HW, D, dnb, hwnb;
    if (gid < 224) { fmap = fmap3; W1 = W13; fw = fw3; C = 1024; HW = 784; D = 512;  dnb = 8;  hwnb = 7; }
    else { gid -= 224; fmap = fmap4; W1 = W14; fw = fw4; C = 2048; HW = 196; D = 1024; dnb = 16; hwnb = 2; }
    int dblk = gid % dnb; gid /= dnb;
    int hwblk = gid % hwnb;
    int b = gid / hwnb;
    int m0 = hwblk * 128, d0 = dblk * 64;
    int tid = threadIdx.x, wave = tid >> 6, lane = tid & 63;
    const float* fb = fmap + (size_t)b * C * HW;

    int am = tid & 127, ac0 = (tid >> 7) * 8;
    int bd = tid >> 3, bc0 = (tid & 7) * 4;
    int hwA = m0 + am;
    bool okA = hwA < HW;
    const float* aptr = fb + (size_t)ac0 * HW + (okA ? hwA : 0);
    const float* bptr = W1 + (size_t)(d0 + bd) * C + bc0;

    float ar[8];
    float4 br;
#pragma unroll
    for (int i = 0; i < 8; ++i) ar[i] = okA ? aptr[(size_t)i * HW] : 0.f;
    br = *(const float4*)bptr;

    f32x4 acc[4];
#pragma unroll
    for (int nr = 0; nr < 4; ++nr) acc[nr] = (f32x4){0.f, 0.f, 0.f, 0.f};

#define CW(bufi)                                                              \
    {                                                                         \
        s16x8 ap;                                                             \
        _Pragma("unroll") for (int i = 0; i < 8; ++i) ap[i] = (short)f2bf(ar[i]); \
        *(s16x8*)&Al[bufi][am * 40 + ac0] = ap;                               \
        s16x4 bp;                                                             \
        bp[0] = (short)f2bf(br.x); bp[1] = (short)f2bf(br.y);                 \
        bp[2] = (short)f2bf(br.z); bp[3] = (short)f2bf(br.w);                 \
        *(s16x4*)&Bl[bufi][bd * 40 + bc0] = bp;                               \
    }

    CW(0);
    __syncthreads();

    int NS = C >> 5;
    int ko = (lane >> 4) * 8, rr = lane & 15;
    for (int s = 0; s < NS; ++s) {
        if (s + 1 < NS) {
            const float* ap2 = aptr + (size_t)(s + 1) * 32 * HW;
#pragma unroll
            for (int i = 0; i < 8; ++i) ar[i] = okA ? ap2[(size_t)i * HW] : 0.f;
            br = *(const float4*)(bptr + (s + 1) * 32);
        }
        int buf = s & 1;
        s16x8 afr = *(s16x8*)&Al[buf][(wave * 16 + rr) * 40 + ko];
        s16x8 bfr[4];
#pragma unroll
        for (int nr = 0; nr < 4; ++nr)
            bfr[nr] = *(s16x8*)&Bl[buf][(nr * 16 + rr) * 40 + ko];
#pragma unroll
        for (int nr = 0; nr < 4; ++nr)
            acc[nr] = __builtin_amdgcn_mfma_f32_16x16x32_bf16(afr, bfr[nr], acc[nr], 0, 0, 0);
        if (s + 1 < NS) CW(buf ^ 1);
        __syncthreads();
    }
#undef CW

    int row4 = (lane >> 4) * 4, col = lane & 15;
#pragma unroll
    for (int j = 0; j < 4; ++j) {
        int mm = m0 + wave * 16 + row4 + j;
        if (mm < HW) {
#pragma unroll
            for (int nr = 0; nr < 4; ++nr)
                fw[((size_t)b * HW + mm) * D + d0 + nr * 16 + col] = acc[nr][j];
        }
    }
}

// ---------------------------------------------------------------------------
// p[b][k][hw] = exp(-2 * sum_d v[d] * rcp(exp2(fw[m,d]*fd2[k,d]) + 1))
// + psum[b][k] += sum of the 4 p values (atomic, for k_pool's normalization)
// ---------------------------------------------------------------------------
__global__ __launch_bounds__(320) void k_score(
    const float* __restrict__ fw3, const float* __restrict__ fd3,
    const float* __restrict__ v3, float* __restrict__ p3, float* __restrict__ ps3,
    const float* __restrict__ fw4, const float* __restrict__ fd4,
    const float* __restrict__ v4, float* __restrict__ p4, float* __restrict__ ps4) {
    __shared__ float fwl[4][1024];
    __shared__ float vl[1024];
    int bid = blockIdx.x;
    const float *fw, *fd, *v; float *p, *psum; int D, HW;
    if (bid < 784) { fw = fw3; fd = fd3; v = v3; p = p3; psum = ps3; D = 512; HW = 784; }
    else { bid -= 784; fw = fw4; fd = fd4; v = v4; p = p4; psum = ps4; D = 1024; HW = 196; }
    int nt = HW >> 2;
    int b = bid / nt, m0 = (bid - b * nt) * 4;
    int tid = threadIdx.x;
    const float* fwg = fw + ((size_t)b * HW + m0) * D;
    int D4 = D >> 2;
    if (tid < D4) {
        ((float4*)vl)[tid] = ((const float4*)v)[tid];
#pragma unroll
        for (int t = 0; t < 4; ++t)
            ((float4*)fwl[t])[tid] = ((const float4*)(fwg + (size_t)t * D))[tid];
    }
    __syncthreads();
    int wave = tid >> 6, lane = tid & 63;
    int kk = lane >> 2, ds = lane & 3;
    int k = wave * 16 + kk;
    const float4* fdp = (const float4*)(fd + (size_t)k * D);
    const float4* vp  = (const float4*)vl;
    const float4* w0p = (const float4*)fwl[0];
    const float4* w1p = (const float4*)fwl[1];
    const float4* w2p = (const float4*)fwl[2];
    const float4* w3p = (const float4*)fwl[3];
    float acc0 = 0.f, acc1 = 0.f, acc2 = 0.f, acc3 = 0.f;
    int NJ = D >> 4;  // groups of 4 float4-chunks; lane ds owns cj%4==ds
    for (int jj = 0; jj < NJ; jj += 2) {
        int c0 = jj * 4 + ds, c1 = c0 + 4;
        float4 f0 = fdp[c0], f1 = fdp[c1];
        float4 va = vp[c0], vb = vp[c1];
        acc0 += t4(w0p[c0], f0, va) + t4(w0p[c1], f1, vb);
        acc1 += t4(w1p[c0], f0, va) + t4(w1p[c1], f1, vb);
        acc2 += t4(w2p[c0], f0, va) + t4(w2p[c1], f1, vb);
        acc3 += t4(w3p[c0], f0, va) + t4(w3p[c1], f1, vb);
    }
    acc0 += __shfl_xor(acc0, 1); acc0 += __shfl_xor(acc0, 2);
    acc1 += __shfl_xor(acc1, 1); acc1 += __shfl_xor(acc1, 2);
    acc2 += __shfl_xor(acc2, 1); acc2 += __shfl_xor(acc2, 2);
    acc3 += __shfl_xor(acc3, 1); acc3 += __shfl_xor(acc3, 2);
    if (ds == 0) {
        const float S = -2.885390081777927f;  // -2 * log2(e) -> exp2
        float4 pv;
        pv.x = __builtin_amdgcn_exp2f(acc0 * S);
        pv.y = __builtin_amdgcn_exp2f(acc1 * S);
        pv.z = __builtin_amdgcn_exp2f(acc2 * S);
        pv.w = __builtin_amdgcn_exp2f(acc3 * S);
        *(float4*)(p + ((size_t)b * K_CLS + k) * HW + m0) = pv;
        atomicAdd(&psum[b * K_CLS + k], (pv.x + pv.y) + (pv.z + pv.w));
    }
}

// ---------------------------------------------------------------------------
// out[b][k][c] = (sum_hw p·fmap) / psum[b,k]
// Tile 40k x 64c, chunk 64 hw. 256 thr = 8 kg (5 k each) x 32 cg (c, c+32).
// All LDS reads b128; fl/pl row stride 68 (=4 mod 32, 16B aligned).
//   s3: blocks [0,128): C=1024 HW=784 ; s4: [128,384): C=2048 HW=196
// ---------------------------------------------------------------------------
#define PCH 64
__global__ __launch_bounds__(256) void k_pool(
    const float* __restrict__ p3, const float* __restrict__ fmap3,
    const float* __restrict__ ps3,
    const float* __restrict__ p4, const float* __restrict__ fmap4,
    const float* __restrict__ ps4, float* __restrict__ out) {
    __shared__ float pl[40][PCH + 4];
    __shared__ float fl[64][PCH + 4];
    int bid = blockIdx.x;
    const float *p, *fmap, *psum; float* o; int C, HW, cnb;
    if (bid < 128) { p = p3; fmap = fmap3; psum = ps3; o = out; C = 1024; HW = 784; cnb = 16; }
    else { bid -= 128; p = p4; fmap = fmap4; psum = ps4; o = out + (size_t)4 * K_CLS * 1024; C = 2048; HW = 196; cnb = 32; }
    int c0 = (bid % cnb) * 64; bid /= cnb;
    int kb = (bid & 1) * 40;
    int b = bid >> 1;
    int tid = threadIdx.x;
    int cg = tid & 31, kg = tid >> 5;  // kg 0..7
    int k_l = kg * 5;
    const float* fb = fmap + ((size_t)b * C + c0) * HW;
    const float* pb = p + ((size_t)b * K_CLS + kb) * HW;
    float acc[5][2] = {};
    int nch = (HW + PCH - 1) / PCH;
    for (int ch = 0; ch < nch; ++ch) {
        int hw0 = ch * PCH;
        for (int i = tid; i < 40 * (PCH / 4); i += 256) {
            int r = i >> 4, cc = (i & 15) * 4;
            int hw = hw0 + cc;
            float4 val = (hw < HW) ? *(const float4*)(pb + (size_t)r * HW + hw)
                                   : make_float4(0.f, 0.f, 0.f, 0.f);
            *(float4*)&pl[r][cc] = val;
        }
        for (int i = tid; i < 64 * (PCH / 4); i += 256) {
            int r = i >> 4, cc = (i & 15) * 4;
            int hw = hw0 + cc;
            float4 val = (hw < HW) ? *(const float4*)(fb + (size_t)r * HW + hw)
                                   : make_float4(0.f, 0.f, 0.f, 0.f);
            *(float4*)&fl[r][cc] = val;
        }
        __syncthreads();
#pragma unroll 4
        for (int jj = 0; jj < PCH / 4; ++jj) {
            float4 fa = *(const float4*)&fl[cg][jj * 4];
            float4 fbv = *(const float4*)&fl[cg + 32][jj * 4];
#pragma unroll
            for (int t = 0; t < 5; ++t) {
                float4 pv = *(const float4*)&pl[k_l + t][jj * 4];
                acc[t][0] += dot4(pv, fa);
                acc[t][1] += dot4(pv, fbv);
            }
        }
        __syncthreads();
    }
#pragma unroll
    for (int t = 0; t < 5; ++t) {
        int k = kb + k_l + t;
        float inv = 1.0f / psum[b * K_CLS + k];
        float* orow = o + ((size_t)b * K_CLS + k) * C + c0;
        orow[cg] = acc[t][0] * inv;
        orow[cg + 32] = acc[t][1] * inv;
    }
}

// ---------------------------------------------------------------------------
extern "C" void kernel_launch(void* const* d_in, const int* in_sizes, int n_in,
                              void* d_out, int out_size, void* d_ws, size_t ws_size,
                              hipStream_t stream) {
    const float* fmap3 = (const float*)d_in[1];
    const float* fmap4 = (const float*)d_in[2];
    const float* word  = (const float*)d_in[3];
    const float* W1_3  = (const float*)d_in[4];
    const float* W2_3  = (const float*)d_in[5];
    const float* W3_3  = (const float*)d_in[6];
    const float* Wa_3  = (const float*)d_in[8];
    const float* W1_4  = (const float*)d_in[10];
    const float* W2_4  = (const float*)d_in[11];
    const float* W3_4  = (const float*)d_in[12];
    const float* Wa_4  = (const float*)d_in[14];
    float* out = (float*)d_out;

    float* ws = (float*)d_ws;
    size_t off = 0;
    float* fw3 = ws + off; off += (size_t)3136 * 512;
    float* fd3 = ws + off; off += (size_t)80 * 512;
    float* v3  = ws + off; off += 512;
    float* sc3 = ws + off; off += (size_t)4 * 80 * 784;
    float* fw4 = ws + off; off += (size_t)784 * 1024;
    float* fd4 = ws + off; off += (size_t)80 * 1024;
    float* v4  = ws + off; off += 1024;
    float* sc4 = ws + off; off += (size_t)4 * 80 * 196;
    float* ps3 = ws + off; off += 320;
    float* ps4 = ws + off; off += 320;

    k_small<<<145, 256, 0, stream>>>(word, W2_3, fd3, W2_4, fd4,
                                     Wa_3, W3_3, v3, Wa_4, W3_4, v4, ps3, ps4);
    k_fw<<<352, 512, 0, stream>>>(fmap3, W1_3, fw3, fmap4, W1_4, fw4);
    k_score<<<980, 320, 0, stream>>>(fw3, fd3, v3, sc3, ps3, fw4, fd4, v4, sc4, ps4);
    k_pool<<<384, 256, 0, stream>>>(sc3, fmap3, ps3, sc4, fmap4, ps4, out);
}